// Round 4
// baseline (172.162 us; speedup 1.0000x reference)
//
#include <hip/hip_runtime.h>
#include <cstdint>
#include <cstddef>

// ---------- types ----------
typedef __bf16 bf16;
typedef __bf16 bf16x8 __attribute__((ext_vector_type(8)));
typedef __bf16 bf16x2 __attribute__((ext_vector_type(2)));
typedef float  floatx4 __attribute__((ext_vector_type(4)));
typedef unsigned uintx4 __attribute__((ext_vector_type(4)));

typedef __attribute__((address_space(1))) void gvoid_t;
typedef __attribute__((address_space(3))) void lvoid_t;

#define MFMA16(a, b, c) __builtin_amdgcn_mfma_f32_16x16x32_bf16((a), (b), (c), 0, 0, 0)

#if __has_builtin(__builtin_amdgcn_exp2f)
#define EXP2(x) __builtin_amdgcn_exp2f(x)
#else
#define EXP2(x) exp2f(x)
#endif

// B=2, S=2048, D=1024, H=16, DH=64; tokens NT=4096; E3=3072
#define S_TOK 2048
#define E3 3072
#define DMODEL 1024

// ---------- fused fp32 -> bf16 convert (X, Wqkv w/ Q-scale, Wout) ----------
#define NX 4194304
#define NWQ 3145728
#define NWO 1048576
__global__ __launch_bounds__(256) void cvt_all(const float* __restrict__ X,
                                               const float* __restrict__ Wq,
                                               const float* __restrict__ Wo,
                                               bf16* __restrict__ Xb,
                                               bf16* __restrict__ Wqb,
                                               bf16* __restrict__ Wob) {
  int i = (blockIdx.x * 256 + threadIdx.x) * 8;
  const float* s;
  bf16* d;
  float sc = 1.0f;
  int off;
  if (i < NX) {
    s = X; d = Xb; off = i;
  } else if (i < NX + NWQ) {
    off = i - NX; s = Wq; d = Wqb;
    int row = off >> 10;  // D=1024 per row; rows with e%192<64 produce Q
    if ((row % 192) < 64) sc = 0.18033688011f;  // 0.125*log2(e) pre-folded
  } else {
    off = i - NX - NWQ; s = Wo; d = Wob;
  }
  const float4* p = (const float4*)(s + off);
  float4 a = p[0], b = p[1];
  bf16x8 o;
  o[0] = (bf16)(a.x * sc); o[1] = (bf16)(a.y * sc);
  o[2] = (bf16)(a.z * sc); o[3] = (bf16)(a.w * sc);
  o[4] = (bf16)(b.x * sc); o[5] = (bf16)(b.y * sc);
  o[6] = (bf16)(b.z * sc); o[7] = (bf16)(b.w * sc);
  *(bf16x8*)(d + off) = o;
}

// ---------- async global->LDS, 16B per lane ----------
__device__ __forceinline__ void gl_lds16(const bf16* g, bf16* l) {
  __builtin_amdgcn_global_load_lds((gvoid_t*)g, (lvoid_t*)l, 16, 0, 0);
}

// ---------- GEMM: BK=64, XOR-swizzled LDS; optional fused V-transpose ----------
// FUSE_V key-slot permutation sigma (within each 32-token group), co-designed
// with attn's swapped-QK^T lane ownership: position p = lgrp*8 + t*4 + r holds
// key t*16 + lgrp*4 + r. Then lane (lrow,lgrp)'s own 8 exps (sc[t][r],
// keys t*16+lgrp*4+r) ARE its PV A-fragment in slot order j=t*4+r — no
// cross-lane exchange needed at all. sigma^-1(key k) = ((k>>2)&3)*8 +
// ((k>>4)&1)*4 + (k&3). Bijective on [0,32).
template <bool OUT_BF16, bool FUSE_V>
__global__ __launch_bounds__(256) void gemm_bt(const bf16* __restrict__ A,
                                               const bf16* __restrict__ Bt,
                                               void* __restrict__ Cv,
                                               bf16* __restrict__ Vt,
                                               int M, int N, int K) {
  __shared__ bf16 sA[128 * 64];  // 16 KB
  __shared__ bf16 sB[128 * 64];  // 16 KB
  const int tid = threadIdx.x;
  const int wv = tid >> 6, lane = tid & 63;
  const int wr = wv >> 1, wc = wv & 1;
  const int lrow = lane & 15, lgrp = lane >> 4;
  const int R0 = blockIdx.y * 128, C0 = blockIdx.x * 128;

  floatx4 acc[4][4] = {};

  const int srow = lane >> 3;
  const int schk = (lane & 7) ^ srow;  // source chunk, swizzle key = row&7
  const bf16* gA = A + (size_t)(R0 + wv * 32 + srow) * K + schk * 8;
  const bf16* gB = Bt + (size_t)(C0 + wv * 32 + srow) * K + schk * 8;
  bf16* lA = sA + wv * 32 * 64;
  bf16* lB = sB + wv * 32 * 64;
  const size_t rs8 = (size_t)8 * K;

  for (int k0 = 0; k0 < K; k0 += 64) {
#pragma unroll
    for (int c = 0; c < 4; c++) {
      gl_lds16(gA + k0 + c * rs8, lA + c * 512);
      gl_lds16(gB + k0 + c * rs8, lB + c * 512);
    }
    __syncthreads();
#pragma unroll
    for (int kk = 0; kk < 2; kk++) {
      bf16x8 af[4], bfr[4];
#pragma unroll
      for (int i = 0; i < 4; i++) {
        int r = wr * 64 + i * 16 + lrow;
        af[i] = *(const bf16x8*)&sA[r * 64 + ((kk * 4 + lgrp) ^ (r & 7)) * 8];
      }
#pragma unroll
      for (int j = 0; j < 4; j++) {
        int r = wc * 64 + j * 16 + lrow;
        bfr[j] = *(const bf16x8*)&sB[r * 64 + ((kk * 4 + lgrp) ^ (r & 7)) * 8];
      }
#pragma unroll
      for (int i = 0; i < 4; i++)
#pragma unroll
        for (int j = 0; j < 4; j++)
          acc[i][j] = MFMA16(af[i], bfr[j], acc[i][j]);
    }
    __syncthreads();
  }

  const int rbase = R0 + wr * 64 + lgrp * 4;
  const int cbase = C0 + wc * 64 + lrow;
  if (OUT_BF16) {
    bf16* C = (bf16*)Cv;
#pragma unroll
    for (int i = 0; i < 4; i++)
#pragma unroll
      for (int j = 0; j < 4; j++) {
        const int col = cbase + j * 16;
        const int m192 = col % 192;
        const int hh = col / 192;
#pragma unroll
        for (int r = 0; r < 4; r++) {
          const int row = rbase + i * 16 + r;
          bf16 val = (bf16)acc[i][j][r];
          bf16* dst;
          if (FUSE_V && m192 >= 128) {
            const int sl = row & 2047;
            const int sl5 = sl & 31;
            // sigma^-1: key k -> stored position ((k>>2)&3)*8 + ((k>>4)&1)*4 + (k&3)
            const int q5 = (((sl5 >> 2) & 3) << 3) | (((sl5 >> 4) & 1) << 2) | (sl5 & 3);
            const int sp = (sl & ~31) | q5;
            dst = Vt + ((size_t)(((row >> 11) * 16 + hh) * 64 + (m192 - 128))) * S_TOK + sp;
          } else {
            dst = C + (size_t)row * N + col;
          }
          *dst = val;
        }
      }
  } else {
    float* C = (float*)Cv;
#pragma unroll
    for (int i = 0; i < 4; i++)
#pragma unroll
      for (int j = 0; j < 4; j++)
#pragma unroll
        for (int r = 0; r < 4; r++)
          C[(size_t)(rbase + i * 16 + r) * N + cbase + j * 16] = acc[i][j][r];
  }
}

// ---------- GEMM 128x64 tile (out-proj: N=1024 -> 512 blocks, 2/CU) ----------
__global__ __launch_bounds__(256) void gemm_bt_n64(const bf16* __restrict__ A,
                                                   const bf16* __restrict__ Bt,
                                                   float* __restrict__ C,
                                                   int M, int N, int K) {
  __shared__ bf16 sA[128 * 64];  // 16 KB
  __shared__ bf16 sB[64 * 64];   //  8 KB
  const int tid = threadIdx.x;
  const int wv = tid >> 6, lane = tid & 63;
  const int wr = wv >> 1, wc = wv & 1;
  const int lrow = lane & 15, lgrp = lane >> 4;
  const int R0 = blockIdx.y * 128, C0 = blockIdx.x * 64;

  floatx4 acc[4][2] = {};

  const int srow = lane >> 3;
  const int schk = (lane & 7) ^ srow;
  const bf16* gA = A + (size_t)(R0 + wv * 32 + srow) * K + schk * 8;
  const bf16* gB = Bt + (size_t)(C0 + wv * 16 + srow) * K + schk * 8;
  bf16* lA = sA + wv * 32 * 64;
  bf16* lB = sB + wv * 16 * 64;
  const size_t rs8 = (size_t)8 * K;

  for (int k0 = 0; k0 < K; k0 += 64) {
#pragma unroll
    for (int c = 0; c < 4; c++) gl_lds16(gA + k0 + c * rs8, lA + c * 512);
#pragma unroll
    for (int c = 0; c < 2; c++) gl_lds16(gB + k0 + c * rs8, lB + c * 512);
    __syncthreads();
#pragma unroll
    for (int kk = 0; kk < 2; kk++) {
      bf16x8 af[4], bfr[2];
#pragma unroll
      for (int i = 0; i < 4; i++) {
        int r = wr * 64 + i * 16 + lrow;
        af[i] = *(const bf16x8*)&sA[r * 64 + ((kk * 4 + lgrp) ^ (r & 7)) * 8];
      }
#pragma unroll
      for (int j = 0; j < 2; j++) {
        int r = wc * 32 + j * 16 + lrow;
        bfr[j] = *(const bf16x8*)&sB[r * 64 + ((kk * 4 + lgrp) ^ (r & 7)) * 8];
      }
#pragma unroll
      for (int i = 0; i < 4; i++)
#pragma unroll
        for (int j = 0; j < 2; j++)
          acc[i][j] = MFMA16(af[i], bfr[j], acc[i][j]);
    }
    __syncthreads();
  }

  const int rbase = R0 + wr * 64 + lgrp * 4;
  const int cbase = C0 + wc * 32 + lrow;
#pragma unroll
  for (int i = 0; i < 4; i++)
#pragma unroll
    for (int j = 0; j < 2; j++)
#pragma unroll
      for (int r = 0; r < 4; r++)
        C[(size_t)(rbase + i * 16 + r) * N + cbase + j * 16] = acc[i][j][r];
}

// ---------- attention v14: 2 blocks/CU (grid-capped occupancy fix) ----------
// v13 postmortem: attn ~44us, Occ 18.8% — grid 256 blocks = 1 block/CU caps
// occupancy at 8 waves/CU even though LDS (64KB) fits 2 blocks. v14: QBLK
// 256->128 (one 16-row tile per wave), grid y 8->16 = 512 blocks = 2/CU =
// 16 waves/CU. Per-wave MFMA:read ratio drops 16:12 -> 8:8 but LDS pipe is
// unsaturated (~10us vs 16.6us MFMA floor); K/V staging doubles but is
// L2-resident (FETCH 12MB, HBM 3.5%). VGPR ~90 fits 4 waves/SIMD budget
// (<=128) -> __launch_bounds__(512,4).
__global__ __launch_bounds__(512, 4) void attn(const bf16* __restrict__ qkv,
                                               const bf16* __restrict__ Vt,
                                               bf16* __restrict__ vals) {
  __shared__ bf16 sK[2][128 * 64];   // 32 KB [buf][key][dh]
  __shared__ bf16 sV[2][64 * 128];   // 32 KB [buf][d][key-slot]

  const int tid = threadIdx.x;
  const int wv = tid >> 6, lane = tid & 63;
  const int lrow = lane & 15, lgrp = lane >> 4;
  const int b = blockIdx.z, h = blockIdx.x;   // x=h: same-(b,h) blocks share XCD
  const int qb = blockIdx.y * 128;

  // K staging: wave w covers key-rows [w*8,w*8+8) and [64+w*8, ...+8)
  const int srow = lane >> 3;          // 0..7
  const int scol = (lane & 7) ^ srow;  // 8-chunk swizzle, key = row&7 = srow
  const bf16* kg0 = qkv + (size_t)(b * S_TOK + wv * 8 + srow) * E3 + h * 192 + 64 + scol * 8;
  // V staging: wave w covers d-rows [w*8,w*8+8) as 2 calls of 4 rows
  const int vrow = lane >> 4;          // 0..3
  const int vchk = lane & 15;          // dest chunk (16-chunk rows)
  const int d0 = wv * 8 + vrow, d1 = d0 + 4;
  const bf16* vg0 = Vt + (size_t)((b * 16 + h) * 64 + d0) * S_TOK + (vchk ^ (d0 & 15)) * 8;
  const bf16* vg1 = Vt + (size_t)((b * 16 + h) * 64 + d1) * S_TOK + (vchk ^ (d1 & 15)) * 8;

  // Q B-fragments (pre-scaled): [n=lane&15][k=lgrp*8+j]
  const bf16* qp = qkv + (size_t)(b * S_TOK + qb + wv * 16) * E3 + h * 192;
  bf16x8 qa[2];
#pragma unroll
  for (int dh = 0; dh < 2; dh++)
    qa[dh] = *(const bf16x8*)(qp + (size_t)lrow * E3 + dh * 32 + lgrp * 8);

  floatx4 O[4] = {};
  float lsum = 0.f;

  auto stage = [&](int buf, int st) {
    const bf16* kg = kg0 + (size_t)st * 128 * E3;
    gl_lds16(kg, &sK[buf][wv * 512]);
    gl_lds16(kg + (size_t)64 * E3, &sK[buf][4096 + wv * 512]);
    gl_lds16(vg0 + st * 128, &sV[buf][wv * 1024]);
    gl_lds16(vg1 + st * 128, &sV[buf][wv * 1024 + 512]);
  };

  // swapped QK^T for 32-key group g: sc[t] = S^T, lane holds
  // rows key = g*32 + t*16 + lgrp*4 + r, col q = lrow
  auto qk_g = [&](int buf, int g, floatx4 (&sc)[2]) {
    bf16x8 kf[2][2];
#pragma unroll
    for (int t = 0; t < 2; t++)
#pragma unroll
      for (int dh = 0; dh < 2; dh++)
        kf[t][dh] = *(const bf16x8*)&sK[buf][(g * 32 + t * 16 + lrow) * 64 +
                                            ((dh * 4 + lgrp) ^ (lrow & 7)) * 8];
    __builtin_amdgcn_s_setprio(1);
    floatx4 a0 = {0.f, 0.f, 0.f, 0.f}, a1 = {0.f, 0.f, 0.f, 0.f};
    a0 = MFMA16(kf[0][0], qa[0], a0);
    a0 = MFMA16(kf[0][1], qa[1], a0);
    a1 = MFMA16(kf[1][0], qa[0], a1);
    a1 = MFMA16(kf[1][1], qa[1], a1);
    sc[0] = a0;
    sc[1] = a1;
    __builtin_amdgcn_s_setprio(0);
  };

  // exp2 + row-sum + pack own 8 exps -> PV A-frag (slot j = t*4+r, sigma'd V)
  auto sm_g = [&](floatx4 (&sc)[2], unsigned (&pfw)[4]) {
    float e0 = EXP2(sc[0][0]), e1 = EXP2(sc[0][1]);
    float e2 = EXP2(sc[0][2]), e3 = EXP2(sc[0][3]);
    float e4 = EXP2(sc[1][0]), e5 = EXP2(sc[1][1]);
    float e6 = EXP2(sc[1][2]), e7 = EXP2(sc[1][3]);
    lsum += ((e0 + e1) + (e2 + e3)) + ((e4 + e5) + (e6 + e7));
    bf16x2 w;
    w[0] = (bf16)e0; w[1] = (bf16)e1;
    pfw[0] = __builtin_bit_cast(unsigned, w);
    w[0] = (bf16)e2; w[1] = (bf16)e3;
    pfw[1] = __builtin_bit_cast(unsigned, w);
    w[0] = (bf16)e4; w[1] = (bf16)e5;
    pfw[2] = __builtin_bit_cast(unsigned, w);
    w[0] = (bf16)e6; w[1] = (bf16)e7;
    pfw[3] = __builtin_bit_cast(unsigned, w);
  };

  auto pv_g = [&](int buf, int g, unsigned (&pfw)[4]) {
    bf16x8 vf[4];
#pragma unroll
    for (int dt = 0; dt < 4; dt++)
      vf[dt] = *(const bf16x8*)&sV[buf][(dt * 16 + lrow) * 128 + ((g * 4 + lgrp) ^ lrow) * 8];
    __builtin_amdgcn_s_setprio(1);
    uintx4 pw = {pfw[0], pfw[1], pfw[2], pfw[3]};
    bf16x8 pf = __builtin_bit_cast(bf16x8, pw);
#pragma unroll
    for (int dt = 0; dt < 4; dt++) O[dt] = MFMA16(pf, vf[dt], O[dt]);
    __builtin_amdgcn_s_setprio(0);
  };

  // skewed schedule: qk(g+1)/sm(g+1) cover pv(g)'s vf-read + cvt latency
  auto compute = [&](int buf) {
    floatx4 scA[2], scB[2];
    unsigned pfA[4], pfB[4];
    qk_g(buf, 0, scA); sm_g(scA, pfA);
    qk_g(buf, 1, scB); sm_g(scB, pfB); pv_g(buf, 0, pfA);
    qk_g(buf, 2, scA); sm_g(scA, pfA); pv_g(buf, 1, pfB);
    qk_g(buf, 3, scB); sm_g(scB, pfB); pv_g(buf, 2, pfA);
    pv_g(buf, 3, pfB);
  };

  stage(0, 0);
  __syncthreads();
#pragma unroll 1
  for (int st = 0; st < 16; st += 2) {
    stage(1, st + 1);
    compute(0);
    __syncthreads();
    if (st + 2 < 16) stage(0, st + 2);
    compute(1);
    __syncthreads();
  }

  // denominator: lane holds partial sum for q = lrow over its lgrp's keys;
  // reduce across lgrp (lane bits 4,5), then route to O's row layout via shfl
  lsum += __shfl_xor(lsum, 16);
  lsum += __shfl_xor(lsum, 32);

  bf16* vout = vals + (size_t)(b * S_TOK + qb + wv * 16) * DMODEL + h * 64;
#pragma unroll
  for (int r = 0; r < 4; r++) {
    float rs = __shfl(lsum, lgrp * 4 + r);
    float rinv = __builtin_amdgcn_rcpf(rs);
#pragma unroll
    for (int dt = 0; dt < 4; dt++)
      vout[(size_t)(lgrp * 4 + r) * DMODEL + dt * 16 + lrow] =
          (bf16)(O[dt][r] * rinv);
  }
}

// ---------- host ----------
extern "C" void kernel_launch(void* const* d_in, const int* in_sizes, int n_in,
                              void* d_out, int out_size, void* d_ws, size_t ws_size,
                              hipStream_t stream) {
  const float* X = (const float*)d_in[0];     // (2,2048,1024)
  const float* Wqkv = (const float*)d_in[1];  // (3072,1024)
  const float* Wout = (const float*)d_in[2];  // (1024,1024)
  float* out = (float*)d_out;                 // (2,2048,1024)

  char* ws = (char*)d_ws;
  bf16* Xb = (bf16*)(ws);                          //  8 MB
  bf16* Wqb = (bf16*)(ws + ((size_t)8 << 20));     //  6 MB
  bf16* Wob = (bf16*)(ws + ((size_t)14 << 20));    //  2 MB
  bf16* qkvb = (bf16*)(ws + ((size_t)16 << 20));   // 24 MB (4096 x 3072; V-part unused)
  bf16* Vt = (bf16*)(ws + ((size_t)40 << 20));     //  8 MB (2*16*64 x 2048)
  bf16* vals = (bf16*)(ws + ((size_t)48 << 20));   //  8 MB (4096 x 1024)

  cvt_all<<<(NX + NWQ + NWO) / 2048, 256, 0, stream>>>(X, Wqkv, Wout, Xb, Wqb, Wob);

  // qkv = X @ Wqkv^T, V-part written straight to Vt (sigma-permuted)
  gemm_bt<true, true><<<dim3(24, 32), 256, 0, stream>>>(Xb, Wqb, qkvb, Vt, 4096, 3072, 1024);

  // grid (h, qb, b): linear%8 = h%8 -> each XCD owns 4 (b,h) pairs' K/V (2MB, L2-fit)
  // 512 blocks = 2/CU = 16 waves/CU
  attn<<<dim3(16, 16, 2), 512, 0, stream>>>(qkvb, Vt, vals);

  // out = vals @ Wout^T : 128x64 tiles -> 512 blocks (2/CU)
  gemm_bt_n64<<<dim3(16, 32), 256, 0, stream>>>(vals, Wob, out, 4096, 1024, 1024);
}

// Round 6
// 167.167 us; speedup vs baseline: 1.0299x; 1.0299x over previous
//
#include <hip/hip_runtime.h>
#include <cstdint>
#include <cstddef>

// ---------- types ----------
typedef __bf16 bf16;
typedef __bf16 bf16x8 __attribute__((ext_vector_type(8)));
typedef __bf16 bf16x4 __attribute__((ext_vector_type(4)));
typedef __bf16 bf16x2 __attribute__((ext_vector_type(2)));
typedef float  floatx4 __attribute__((ext_vector_type(4)));
typedef unsigned uintx4 __attribute__((ext_vector_type(4)));

typedef __attribute__((address_space(1))) void gvoid_t;
typedef __attribute__((address_space(3))) void lvoid_t;

#define MFMA16(a, b, c) __builtin_amdgcn_mfma_f32_16x16x32_bf16((a), (b), (c), 0, 0, 0)

#if __has_builtin(__builtin_amdgcn_exp2f)
#define EXP2(x) __builtin_amdgcn_exp2f(x)
#else
#define EXP2(x) exp2f(x)
#endif

// B=2, S=2048, D=1024, H=16, DH=64; tokens NT=4096; E3=3072
#define S_TOK 2048
#define E3 3072
#define DMODEL 1024

// ---------- fused fp32 -> bf16 convert (X, Wqkv w/ Q-scale, Wout) ----------
#define NX 4194304
#define NWQ 3145728
#define NWO 1048576
__global__ __launch_bounds__(256) void cvt_all(const float* __restrict__ X,
                                               const float* __restrict__ Wq,
                                               const float* __restrict__ Wo,
                                               bf16* __restrict__ Xb,
                                               bf16* __restrict__ Wqb,
                                               bf16* __restrict__ Wob) {
  int i = (blockIdx.x * 256 + threadIdx.x) * 8;
  const float* s;
  bf16* d;
  float sc = 1.0f;
  int off;
  if (i < NX) {
    s = X; d = Xb; off = i;
  } else if (i < NX + NWQ) {
    off = i - NX; s = Wq; d = Wqb;
    int row = off >> 10;  // D=1024 per row; rows with e%192<64 produce Q
    if ((row % 192) < 64) sc = 0.18033688011f;  // 0.125*log2(e) pre-folded
  } else {
    off = i - NX - NWQ; s = Wo; d = Wob;
  }
  const float4* p = (const float4*)(s + off);
  float4 a = p[0], b = p[1];
  bf16x8 o;
  o[0] = (bf16)(a.x * sc); o[1] = (bf16)(a.y * sc);
  o[2] = (bf16)(a.z * sc); o[3] = (bf16)(a.w * sc);
  o[4] = (bf16)(b.x * sc); o[5] = (bf16)(b.y * sc);
  o[6] = (bf16)(b.z * sc); o[7] = (bf16)(b.w * sc);
  *(bf16x8*)(d + off) = o;
}

// ---------- async global->LDS, 16B per lane ----------
__device__ __forceinline__ void gl_lds16(const bf16* g, bf16* l) {
  __builtin_amdgcn_global_load_lds((gvoid_t*)g, (lvoid_t*)l, 16, 0, 0);
}

// ---------- GEMM: BK=64, XOR-swizzled LDS; fused Q/K/V routing epilogue ----
// Workspace-safety note (R5 container failure): v15 had grown the workspace
// to 64 MB (> proven 56 MB bound) — possible OOB fault. v16 compacts K into
// Kc[(b*16+h)][key][64] (8 MB; was 24 MB full-qkv layout) -> total 48 MB.
// Epilogue routing:
//  - Q -> Qt[(b*16+h)*64+dh][token] (token-transposed), bf16x4 b64 stores
//  - V -> Vt sigma-permuted, bf16x4 b64 stores (sigma keeps 4-runs contiguous)
//  - K -> Kc row-major [key][dh] (attn gl_lds16 staging needs dh-contiguous)
// sigma (within each 32-token group): position p = lgrp*8 + t*4 + r holds
// key t*16 + lgrp*4 + r; sigma^-1(k) = ((k>>2)&3)*8 + ((k>>4)&1)*4 + (k&3).
template <bool OUT_BF16, bool FUSE_V>
__global__ __launch_bounds__(256) void gemm_bt(const bf16* __restrict__ A,
                                               const bf16* __restrict__ Bt,
                                               void* __restrict__ Cv,
                                               bf16* __restrict__ Vt,
                                               bf16* __restrict__ Qt,
                                               int M, int N, int K) {
  __shared__ bf16 sA[128 * 64];  // 16 KB
  __shared__ bf16 sB[128 * 64];  // 16 KB
  const int tid = threadIdx.x;
  const int wv = tid >> 6, lane = tid & 63;
  const int wr = wv >> 1, wc = wv & 1;
  const int lrow = lane & 15, lgrp = lane >> 4;
  const int R0 = blockIdx.y * 128, C0 = blockIdx.x * 128;

  floatx4 acc[4][4] = {};

  const int srow = lane >> 3;
  const int schk = (lane & 7) ^ srow;  // source chunk, swizzle key = row&7
  const bf16* gA = A + (size_t)(R0 + wv * 32 + srow) * K + schk * 8;
  const bf16* gB = Bt + (size_t)(C0 + wv * 32 + srow) * K + schk * 8;
  bf16* lA = sA + wv * 32 * 64;
  bf16* lB = sB + wv * 32 * 64;
  const size_t rs8 = (size_t)8 * K;

  for (int k0 = 0; k0 < K; k0 += 64) {
#pragma unroll
    for (int c = 0; c < 4; c++) {
      gl_lds16(gA + k0 + c * rs8, lA + c * 512);
      gl_lds16(gB + k0 + c * rs8, lB + c * 512);
    }
    __syncthreads();
#pragma unroll
    for (int kk = 0; kk < 2; kk++) {
      bf16x8 af[4], bfr[4];
#pragma unroll
      for (int i = 0; i < 4; i++) {
        int r = wr * 64 + i * 16 + lrow;
        af[i] = *(const bf16x8*)&sA[r * 64 + ((kk * 4 + lgrp) ^ (r & 7)) * 8];
      }
#pragma unroll
      for (int j = 0; j < 4; j++) {
        int r = wc * 64 + j * 16 + lrow;
        bfr[j] = *(const bf16x8*)&sB[r * 64 + ((kk * 4 + lgrp) ^ (r & 7)) * 8];
      }
#pragma unroll
      for (int i = 0; i < 4; i++)
#pragma unroll
        for (int j = 0; j < 4; j++)
          acc[i][j] = MFMA16(af[i], bfr[j], acc[i][j]);
    }
    __syncthreads();
  }

  const int rbase = R0 + wr * 64 + lgrp * 4;
  const int cbase = C0 + wc * 64 + lrow;
  if (OUT_BF16) {
    const int bb = R0 >> 11;         // batch (blocks never cross the 2048 line)
    const int tokb0 = rbase & 2047;  // within-batch token base (i adds 16)
#pragma unroll
    for (int j = 0; j < 4; j++) {
      const int col = cbase + j * 16;
      const int m192 = col % 192;
      const int hh = col / 192;
      if (FUSE_V && m192 < 64) {
        // Q: token-transposed Qt, 4 tokens per b64 store
        bf16* qdst = Qt + (size_t)((bb * 16 + hh) * 64 + m192) * S_TOK + tokb0;
#pragma unroll
        for (int i = 0; i < 4; i++) {
          bf16x4 v;
          v[0] = (bf16)acc[i][j][0]; v[1] = (bf16)acc[i][j][1];
          v[2] = (bf16)acc[i][j][2]; v[3] = (bf16)acc[i][j][3];
          *(bf16x4*)(qdst + i * 16) = v;
        }
      } else if (FUSE_V && m192 >= 128) {
        // V: sigma-permuted Vt, 4 slots per b64 store
        bf16* vdst = Vt + (size_t)((bb * 16 + hh) * 64 + (m192 - 128)) * S_TOK;
#pragma unroll
        for (int i = 0; i < 4; i++) {
          const int t0 = tokb0 + i * 16;
          const int b5 = t0 & 31;
          const int q5 = (((b5 >> 2) & 3) << 3) | (((b5 >> 4) & 1) << 2);
          bf16x4 v;
          v[0] = (bf16)acc[i][j][0]; v[1] = (bf16)acc[i][j][1];
          v[2] = (bf16)acc[i][j][2]; v[3] = (bf16)acc[i][j][3];
          *(bf16x4*)(vdst + ((t0 & ~31) | q5)) = v;
        }
      } else if (FUSE_V) {
        // K -> compact Kc[(bb*16+hh)][token][dh] (row-major per key)
        bf16* kdst = (bf16*)Cv + ((size_t)((bb * 16 + hh) * 2048 + tokb0)) * 64 + (m192 - 64);
#pragma unroll
        for (int i = 0; i < 4; i++)
#pragma unroll
          for (int r = 0; r < 4; r++)
            kdst[(size_t)(i * 16 + r) * 64] = (bf16)acc[i][j][r];
      } else {
        bf16* C = (bf16*)Cv;
#pragma unroll
        for (int i = 0; i < 4; i++)
#pragma unroll
          for (int r = 0; r < 4; r++)
            C[(size_t)(rbase + i * 16 + r) * N + col] = (bf16)acc[i][j][r];
      }
    }
  } else {
    float* C = (float*)Cv;
#pragma unroll
    for (int i = 0; i < 4; i++)
#pragma unroll
      for (int j = 0; j < 4; j++)
#pragma unroll
        for (int r = 0; r < 4; r++)
          C[(size_t)(rbase + i * 16 + r) * N + cbase + j * 16] = acc[i][j][r];
  }
}

// ---------- GEMM 128x64 tile (out-proj: N=1024 -> 512 blocks, 2/CU) ----------
__global__ __launch_bounds__(256) void gemm_bt_n64(const bf16* __restrict__ A,
                                                   const bf16* __restrict__ Bt,
                                                   float* __restrict__ C,
                                                   int M, int N, int K) {
  __shared__ bf16 sA[128 * 64];  // 16 KB
  __shared__ bf16 sB[64 * 64];   //  8 KB
  const int tid = threadIdx.x;
  const int wv = tid >> 6, lane = tid & 63;
  const int wr = wv >> 1, wc = wv & 1;
  const int lrow = lane & 15, lgrp = lane >> 4;
  const int R0 = blockIdx.y * 128, C0 = blockIdx.x * 64;

  floatx4 acc[4][2] = {};

  const int srow = lane >> 3;
  const int schk = (lane & 7) ^ srow;
  const bf16* gA = A + (size_t)(R0 + wv * 32 + srow) * K + schk * 8;
  const bf16* gB = Bt + (size_t)(C0 + wv * 16 + srow) * K + schk * 8;
  bf16* lA = sA + wv * 32 * 64;
  bf16* lB = sB + wv * 16 * 64;
  const size_t rs8 = (size_t)8 * K;

  for (int k0 = 0; k0 < K; k0 += 64) {
#pragma unroll
    for (int c = 0; c < 4; c++) gl_lds16(gA + k0 + c * rs8, lA + c * 512);
#pragma unroll
    for (int c = 0; c < 2; c++) gl_lds16(gB + k0 + c * rs8, lB + c * 512);
    __syncthreads();
#pragma unroll
    for (int kk = 0; kk < 2; kk++) {
      bf16x8 af[4], bfr[2];
#pragma unroll
      for (int i = 0; i < 4; i++) {
        int r = wr * 64 + i * 16 + lrow;
        af[i] = *(const bf16x8*)&sA[r * 64 + ((kk * 4 + lgrp) ^ (r & 7)) * 8];
      }
#pragma unroll
      for (int j = 0; j < 2; j++) {
        int r = wc * 32 + j * 16 + lrow;
        bfr[j] = *(const bf16x8*)&sB[r * 64 + ((kk * 4 + lgrp) ^ (r & 7)) * 8];
      }
#pragma unroll
      for (int i = 0; i < 4; i++)
#pragma unroll
        for (int j = 0; j < 2; j++)
          acc[i][j] = MFMA16(af[i], bfr[j], acc[i][j]);
    }
    __syncthreads();
  }

  const int rbase = R0 + wr * 64 + lgrp * 4;
  const int cbase = C0 + wc * 32 + lrow;
#pragma unroll
  for (int i = 0; i < 4; i++)
#pragma unroll
    for (int j = 0; j < 2; j++)
#pragma unroll
      for (int r = 0; r < 4; r++)
        C[(size_t)(rbase + i * 16 + r) * N + cbase + j * 16] = acc[i][j][r];
}

// ---------- attention v16: compact-K staging + token-transposed Qt ----------
// Structure of v14 (2 blocks/CU, swapped QK^T, zero-exchange P).
// K now staged from Kc[(b*16+h)][key][64]: each gl_lds16 reads a contiguous
// 1 KB block; per-(b,h) K is 256 KB contiguous (L2-friendly). Staging swizzle
// invariant preserved: LDS[row][c] = Kglobal[row][c^(row&7)] (dest chunk
// lane&7, source chunk (lane&7)^srow), kf un-swizzles with ^(lrow&7).
__global__ __launch_bounds__(512, 4) void attn(const bf16* __restrict__ Kc,
                                               const bf16* __restrict__ Vt,
                                               const bf16* __restrict__ Qt,
                                               bf16* __restrict__ vals) {
  __shared__ bf16 sK[2][128 * 64];   // 32 KB [buf][key][dh]
  __shared__ bf16 sV[2][64 * 128];   // 32 KB [buf][d][key-slot]

  const int tid = threadIdx.x;
  const int wv = tid >> 6, lane = tid & 63;
  const int lrow = lane & 15, lgrp = lane >> 4;
  const int b = blockIdx.z, h = blockIdx.x;   // x=h: same-(b,h) blocks share XCD
  const int qb = blockIdx.y * 128;

  // K staging: wave w covers key-rows [w*8,w*8+8) and [64+w*8, ...+8)
  const int srow = lane >> 3;          // 0..7
  const int scol = (lane & 7) ^ srow;  // 8-chunk swizzle, key = row&7 = srow
  const bf16* kg0 = Kc + (size_t)((b * 16 + h) * 2048 + wv * 8 + srow) * 64 + scol * 8;
  // V staging: wave w covers d-rows [w*8,w*8+8) as 2 calls of 4 rows
  const int vrow = lane >> 4;          // 0..3
  const int vchk = lane & 15;          // dest chunk (16-chunk rows)
  const int d0 = wv * 8 + vrow, d1 = d0 + 4;
  const bf16* vg0 = Vt + (size_t)((b * 16 + h) * 64 + d0) * S_TOK + (vchk ^ (d0 & 15)) * 8;
  const bf16* vg1 = Vt + (size_t)((b * 16 + h) * 64 + d1) * S_TOK + (vchk ^ (d1 & 15)) * 8;

  // Q B-fragments (pre-scaled) from Qt: qa[dh][j] = Qt[dh*32+lgrp*8+j][tok]
  const bf16* qtp = Qt + (size_t)((b * 16 + h) * 64) * S_TOK + (qb + wv * 16 + lrow);
  bf16x8 qa[2];
#pragma unroll
  for (int dh = 0; dh < 2; dh++)
#pragma unroll
    for (int j = 0; j < 8; j++)
      qa[dh][j] = qtp[(size_t)(dh * 32 + lgrp * 8 + j) * S_TOK];

  floatx4 O[4] = {};
  float lsum = 0.f;

  auto stage = [&](int buf, int st) {
    const bf16* kg = kg0 + (size_t)st * 128 * 64;
    gl_lds16(kg, &sK[buf][wv * 512]);
    gl_lds16(kg + 64 * 64, &sK[buf][4096 + wv * 512]);
    gl_lds16(vg0 + st * 128, &sV[buf][wv * 1024]);
    gl_lds16(vg1 + st * 128, &sV[buf][wv * 1024 + 512]);
  };

  // swapped QK^T for 32-key group g: sc[t] = S^T, lane holds
  // rows key = g*32 + t*16 + lgrp*4 + r, col q = lrow
  auto qk_g = [&](int buf, int g, floatx4 (&sc)[2]) {
    bf16x8 kf[2][2];
#pragma unroll
    for (int t = 0; t < 2; t++)
#pragma unroll
      for (int dh = 0; dh < 2; dh++)
        kf[t][dh] = *(const bf16x8*)&sK[buf][(g * 32 + t * 16 + lrow) * 64 +
                                            ((dh * 4 + lgrp) ^ (lrow & 7)) * 8];
    __builtin_amdgcn_s_setprio(1);
    floatx4 a0 = {0.f, 0.f, 0.f, 0.f}, a1 = {0.f, 0.f, 0.f, 0.f};
    a0 = MFMA16(kf[0][0], qa[0], a0);
    a0 = MFMA16(kf[0][1], qa[1], a0);
    a1 = MFMA16(kf[1][0], qa[0], a1);
    a1 = MFMA16(kf[1][1], qa[1], a1);
    sc[0] = a0;
    sc[1] = a1;
    __builtin_amdgcn_s_setprio(0);
  };

  // exp2 + row-sum + pack own 8 exps -> PV A-frag (slot j = t*4+r, sigma'd V)
  auto sm_g = [&](floatx4 (&sc)[2], unsigned (&pfw)[4]) {
    float e0 = EXP2(sc[0][0]), e1 = EXP2(sc[0][1]);
    float e2 = EXP2(sc[0][2]), e3 = EXP2(sc[0][3]);
    float e4 = EXP2(sc[1][0]), e5 = EXP2(sc[1][1]);
    float e6 = EXP2(sc[1][2]), e7 = EXP2(sc[1][3]);
    lsum += ((e0 + e1) + (e2 + e3)) + ((e4 + e5) + (e6 + e7));
    bf16x2 w;
    w[0] = (bf16)e0; w[1] = (bf16)e1;
    pfw[0] = __builtin_bit_cast(unsigned, w);
    w[0] = (bf16)e2; w[1] = (bf16)e3;
    pfw[1] = __builtin_bit_cast(unsigned, w);
    w[0] = (bf16)e4; w[1] = (bf16)e5;
    pfw[2] = __builtin_bit_cast(unsigned, w);
    w[0] = (bf16)e6; w[1] = (bf16)e7;
    pfw[3] = __builtin_bit_cast(unsigned, w);
  };

  auto pv_g = [&](int buf, int g, unsigned (&pfw)[4]) {
    bf16x8 vf[4];
#pragma unroll
    for (int dt = 0; dt < 4; dt++)
      vf[dt] = *(const bf16x8*)&sV[buf][(dt * 16 + lrow) * 128 + ((g * 4 + lgrp) ^ lrow) * 8];
    __builtin_amdgcn_s_setprio(1);
    uintx4 pw = {pfw[0], pfw[1], pfw[2], pfw[3]};
    bf16x8 pf = __builtin_bit_cast(bf16x8, pw);
#pragma unroll
    for (int dt = 0; dt < 4; dt++) O[dt] = MFMA16(pf, vf[dt], O[dt]);
    __builtin_amdgcn_s_setprio(0);
  };

  // skewed schedule: qk(g+1)/sm(g+1) cover pv(g)'s vf-read + cvt latency
  auto compute = [&](int buf) {
    floatx4 scA[2], scB[2];
    unsigned pfA[4], pfB[4];
    qk_g(buf, 0, scA); sm_g(scA, pfA);
    qk_g(buf, 1, scB); sm_g(scB, pfB); pv_g(buf, 0, pfA);
    qk_g(buf, 2, scA); sm_g(scA, pfA); pv_g(buf, 1, pfB);
    qk_g(buf, 3, scB); sm_g(scB, pfB); pv_g(buf, 2, pfA);
    pv_g(buf, 3, pfB);
  };

  stage(0, 0);
  __syncthreads();
#pragma unroll 1
  for (int st = 0; st < 16; st += 2) {
    stage(1, st + 1);
    compute(0);
    __syncthreads();
    if (st + 2 < 16) stage(0, st + 2);
    compute(1);
    __syncthreads();
  }

  // denominator: lane holds partial sum for q = lrow over its lgrp's keys;
  // reduce across lgrp (lane bits 4,5), then route to O's row layout via shfl
  lsum += __shfl_xor(lsum, 16);
  lsum += __shfl_xor(lsum, 32);

  bf16* vout = vals + (size_t)(b * S_TOK + qb + wv * 16) * DMODEL + h * 64;
#pragma unroll
  for (int r = 0; r < 4; r++) {
    float rs = __shfl(lsum, lgrp * 4 + r);
    float rinv = __builtin_amdgcn_rcpf(rs);
#pragma unroll
    for (int dt = 0; dt < 4; dt++)
      vout[(size_t)(lgrp * 4 + r) * DMODEL + dt * 16 + lrow] =
          (bf16)(O[dt][r] * rinv);
  }
}

// ---------- host ----------
extern "C" void kernel_launch(void* const* d_in, const int* in_sizes, int n_in,
                              void* d_out, int out_size, void* d_ws, size_t ws_size,
                              hipStream_t stream) {
  const float* X = (const float*)d_in[0];     // (2,2048,1024)
  const float* Wqkv = (const float*)d_in[1];  // (3072,1024)
  const float* Wout = (const float*)d_in[2];  // (1024,1024)
  float* out = (float*)d_out;                 // (2,2048,1024)

  // 48 MB total (proven-safe bound from rounds 0-4 was 56 MB)
  char* ws = (char*)d_ws;
  bf16* Xb = (bf16*)(ws);                          //  8 MB
  bf16* Wqb = (bf16*)(ws + ((size_t)8 << 20));     //  6 MB
  bf16* Wob = (bf16*)(ws + ((size_t)14 << 20));    //  2 MB
  bf16* Kc = (bf16*)(ws + ((size_t)16 << 20));     //  8 MB (2*16 x 2048 x 64)
  bf16* Vt = (bf16*)(ws + ((size_t)24 << 20));     //  8 MB (2*16*64 x 2048)
  bf16* Qt = (bf16*)(ws + ((size_t)32 << 20));     //  8 MB (2*16*64 x 2048)
  bf16* vals = (bf16*)(ws + ((size_t)40 << 20));   //  8 MB (4096 x 1024)

  cvt_all<<<(NX + NWQ + NWO) / 2048, 256, 0, stream>>>(X, Wqkv, Wout, Xb, Wqb, Wob);

  // qkv = X @ Wqkv^T; Q -> Qt (token-transposed), V -> Vt (sigma), K -> Kc (compact)
  gemm_bt<true, true><<<dim3(24, 32), 256, 0, stream>>>(Xb, Wqb, Kc, Vt, Qt, 4096, 3072, 1024);

  // grid (h, qb, b): linear%8 = h%8 -> each XCD owns 4 (b,h) pairs' K/V (L2-fit)
  // 512 blocks = 2/CU = 16 waves/CU
  attn<<<dim3(16, 16, 2), 512, 0, stream>>>(Kc, Vt, Qt, vals);

  // out = vals @ Wout^T : 128x64 tiles -> 512 blocks (2/CU)
  gemm_bt_n64<<<dim3(16, 32), 256, 0, stream>>>(vals, Wob, out, 4096, 1024, 1024);
}